// Round 1
// baseline (17.807 us; speedup 1.0000x reference)
//
#include <hip/hip_runtime.h>
#include <math.h>

// Problem: embeddings (512x128, unused beyond V), site_positions (8192x16,
// unused beyond S), log_Q (4x4). Output = broadcast of the stationary
// distribution of Q to (V=512, S=8192, A=4) fp32 = 16,777,216 floats.
//
// Q = R - I where R = row-normalized exp(log_Q) with zero diagonal.
// Stationary pi: pi Q = 0, sum(pi) = 1. Closed form via adjugate:
// pi_j = det(minor_jj(Q)) / sum_k det(minor_kk(Q)).

__device__ __forceinline__ float det3(float a00, float a01, float a02,
                                      float a10, float a11, float a12,
                                      float a20, float a21, float a22) {
    return a00 * (a11 * a22 - a12 * a21)
         - a01 * (a10 * a22 - a12 * a20)
         + a02 * (a10 * a21 - a11 * a20);
}

__global__ __launch_bounds__(256)
void stat_broadcast_kernel(const float* __restrict__ logQ,
                           float* __restrict__ out,
                           int n_total) {
    // ---- compute pi (uniform across all threads; branch-free; registers only)
    float q[16];
    #pragma unroll
    for (int i = 0; i < 4; ++i) {
        float e0 = (i == 0) ? 0.0f : __expf(logQ[i * 4 + 0]);
        float e1 = (i == 1) ? 0.0f : __expf(logQ[i * 4 + 1]);
        float e2 = (i == 2) ? 0.0f : __expf(logQ[i * 4 + 2]);
        float e3 = (i == 3) ? 0.0f : __expf(logQ[i * 4 + 3]);
        float inv = 1.0f / (e0 + e1 + e2 + e3);
        q[i * 4 + 0] = e0 * inv;
        q[i * 4 + 1] = e1 * inv;
        q[i * 4 + 2] = e2 * inv;
        q[i * 4 + 3] = e3 * inv;
        q[i * 4 + i] = -1.0f;   // diag of Q = -1
    }

    // det of Q with row j and column j deleted (static indices only)
    float m0 = det3(q[5],  q[6],  q[7],
                    q[9],  q[10], q[11],
                    q[13], q[14], q[15]);
    float m1 = det3(q[0],  q[2],  q[3],
                    q[8],  q[10], q[11],
                    q[12], q[14], q[15]);
    float m2 = det3(q[0],  q[1],  q[3],
                    q[4],  q[5],  q[7],
                    q[12], q[13], q[15]);
    float m3 = det3(q[0],  q[1],  q[2],
                    q[4],  q[5],  q[6],
                    q[8],  q[9],  q[10]);

    float invs = 1.0f / (m0 + m1 + m2 + m3);   // minors share sign; ratio > 0
    float4 v;
    v.x = m0 * invs;
    v.y = m1 * invs;
    v.z = m2 * invs;
    v.w = m3 * invs;

    // ---- broadcast fill: innermost dim A=4 => every 16B group == v
    float4* __restrict__ out4 = reinterpret_cast<float4*>(out);
    int n4 = n_total >> 2;
    int gid = blockIdx.x * blockDim.x + threadIdx.x;
    int stride = gridDim.x * blockDim.x;
    for (int i = gid; i < n4; i += stride) {
        out4[i] = v;
    }

    // tail (n_total % 4) — never taken for this problem (n_total = V*S*4),
    // kept for safety
    int tail = n4 << 2;
    for (int t = tail + gid; t < n_total; t += stride) {
        int r = t & 3;
        out[t] = (r == 0) ? v.x : (r == 1) ? v.y : (r == 2) ? v.z : v.w;
    }
}

extern "C" void kernel_launch(void* const* d_in, const int* in_sizes, int n_in,
                              void* d_out, int out_size, void* d_ws, size_t ws_size,
                              hipStream_t stream) {
    // inputs (setup_inputs order): 0: embeddings (unused), 1: site_positions
    // (unused), 2: log_Q_matrix (4x4 f32)
    const float* logQ = (const float*)d_in[2];
    float* out = (float*)d_out;

    const int block = 256;
    int n4 = out_size >> 2;
    int blocks = (n4 + block - 1) / block;
    if (blocks > 2048) blocks = 2048;   // grid-stride the rest (G11)
    if (blocks < 1) blocks = 1;

    stat_broadcast_kernel<<<blocks, block, 0, stream>>>(logQ, out, out_size);
}

// Round 2
// 16.634 us; speedup vs baseline: 1.0705x; 1.0705x over previous
//
#include <hip/hip_runtime.h>
#include <math.h>

// Output = broadcast of the stationary distribution pi of a 4x4 CTMC
// generator Q to (V=512, S=8192, A=4) fp32 = 67.1 MB of pure writes.
// pi_j = det(minor_jj(Q)) / sum_k det(minor_kk(Q))  (adjugate / Markov
// tree theorem) -- no expm needed, error ~1e-6 << 5.1e-3 threshold.

__device__ __forceinline__ float det3(float a00, float a01, float a02,
                                      float a10, float a11, float a12,
                                      float a20, float a21, float a22) {
    return a00 * (a11 * a22 - a12 * a21)
         - a01 * (a10 * a22 - a12 * a20)
         + a02 * (a10 * a21 - a11 * a20);
}

__global__ __launch_bounds__(256)
void stat_broadcast_kernel(const float* __restrict__ logQ,
                           float* __restrict__ out,
                           int n4, int n_total) {
    // ---- pi: load all 16 logits as 4x float4 (short prologue chain)
    const float4* __restrict__ q4 = reinterpret_cast<const float4*>(logQ);
    float4 r0 = q4[0], r1 = q4[1], r2 = q4[2], r3 = q4[3];

    float q[16];
    {
        // row 0: diag element zeroed before normalize
        float e1 = __expf(r0.y), e2 = __expf(r0.z), e3 = __expf(r0.w);
        float inv = 1.0f / (e1 + e2 + e3);
        q[0] = -1.0f; q[1] = e1 * inv; q[2] = e2 * inv; q[3] = e3 * inv;
    }
    {
        float e0 = __expf(r1.x), e2 = __expf(r1.z), e3 = __expf(r1.w);
        float inv = 1.0f / (e0 + e2 + e3);
        q[4] = e0 * inv; q[5] = -1.0f; q[6] = e2 * inv; q[7] = e3 * inv;
    }
    {
        float e0 = __expf(r2.x), e1 = __expf(r2.y), e3 = __expf(r2.w);
        float inv = 1.0f / (e0 + e1 + e3);
        q[8] = e0 * inv; q[9] = e1 * inv; q[10] = -1.0f; q[11] = e3 * inv;
    }
    {
        float e0 = __expf(r3.x), e1 = __expf(r3.y), e2 = __expf(r3.z);
        float inv = 1.0f / (e0 + e1 + e2);
        q[12] = e0 * inv; q[13] = e1 * inv; q[14] = e2 * inv; q[15] = -1.0f;
    }

    // principal 3x3 minors (static indices only -> registers, no scratch)
    float m0 = det3(q[5],  q[6],  q[7],
                    q[9],  q[10], q[11],
                    q[13], q[14], q[15]);
    float m1 = det3(q[0],  q[2],  q[3],
                    q[8],  q[10], q[11],
                    q[12], q[14], q[15]);
    float m2 = det3(q[0],  q[1],  q[3],
                    q[4],  q[5],  q[7],
                    q[12], q[13], q[15]);
    float m3 = det3(q[0],  q[1],  q[2],
                    q[4],  q[5],  q[6],
                    q[8],  q[9],  q[10]);

    float invs = 1.0f / (m0 + m1 + m2 + m3);
    float4 v;
    v.x = m0 * invs;
    v.y = m1 * invs;
    v.z = m2 * invs;
    v.w = m3 * invs;

    // ---- broadcast fill: exact block-chunked, fully unrolled 8 stores.
    // Each block owns 2048 consecutive float4 (32 KB); each thread issues
    // 8 independent global_store_dwordx4 (no loop-carried branch).
    float4* __restrict__ out4 = reinterpret_cast<float4*>(out);
    const int CHUNK = 2048;                       // 256 threads * 8
    int base = blockIdx.x * CHUNK + (int)threadIdx.x;
    #pragma unroll
    for (int k = 0; k < 8; ++k) {
        int i = base + k * 256;
        if (i < n4) out4[i] = v;                  // uniformly true except tail block
    }

    // scalar tail (n_total % 4) — never taken for this problem
    int tail = n4 << 2;
    if (tail < n_total) {
        int t = tail + blockIdx.x * blockDim.x + threadIdx.x;
        if (t < n_total) {
            int r = t & 3;
            out[t] = (r == 0) ? v.x : (r == 1) ? v.y : (r == 2) ? v.z : v.w;
        }
    }
}

extern "C" void kernel_launch(void* const* d_in, const int* in_sizes, int n_in,
                              void* d_out, int out_size, void* d_ws, size_t ws_size,
                              hipStream_t stream) {
    // inputs: 0: embeddings (unused), 1: site_positions (unused),
    //         2: log_Q_matrix (4x4 f32)
    const float* logQ = (const float*)d_in[2];
    float* out = (float*)d_out;

    int n4 = out_size >> 2;                       // 4,194,304 float4
    const int CHUNK = 2048;
    int blocks = (n4 + CHUNK - 1) / CHUNK;        // 2048 blocks exactly
    if (blocks < 1) blocks = 1;

    stat_broadcast_kernel<<<blocks, 256, 0, stream>>>(logQ, out, n4, out_size);
}

// Round 4
// 16.144 us; speedup vs baseline: 1.1030x; 1.0304x over previous
//
#include <hip/hip_runtime.h>
#include <math.h>

// Output = broadcast of the stationary distribution pi of a 4x4 CTMC
// generator Q to (V=512, S=8192, A=4) fp32 = 67.1 MB of pure writes.
// pi_j = det(minor_jj(Q)) / sum_k det(minor_kk(Q))  (adjugate / Markov
// tree theorem) -- no expm needed, error ~1e-6 << 5.1e-3 threshold.
//
// Round 4: nontemporal stores via native ext_vector_type (HIP float4 is a
// class and __builtin_nontemporal_store rejects it) + exact-cover body.

typedef float f32x4 __attribute__((ext_vector_type(4)));

__device__ __forceinline__ float det3(float a00, float a01, float a02,
                                      float a10, float a11, float a12,
                                      float a20, float a21, float a22) {
    return a00 * (a11 * a22 - a12 * a21)
         - a01 * (a10 * a22 - a12 * a20)
         + a02 * (a10 * a21 - a11 * a20);
}

__device__ __forceinline__ f32x4 compute_pi(const float* __restrict__ logQ) {
    const f32x4* __restrict__ q4 = reinterpret_cast<const f32x4*>(logQ);
    f32x4 r0 = q4[0], r1 = q4[1], r2 = q4[2], r3 = q4[3];

    float q[16];
    {
        float e1 = __expf(r0.y), e2 = __expf(r0.z), e3 = __expf(r0.w);
        float inv = 1.0f / (e1 + e2 + e3);
        q[0] = -1.0f; q[1] = e1 * inv; q[2] = e2 * inv; q[3] = e3 * inv;
    }
    {
        float e0 = __expf(r1.x), e2 = __expf(r1.z), e3 = __expf(r1.w);
        float inv = 1.0f / (e0 + e2 + e3);
        q[4] = e0 * inv; q[5] = -1.0f; q[6] = e2 * inv; q[7] = e3 * inv;
    }
    {
        float e0 = __expf(r2.x), e1 = __expf(r2.y), e3 = __expf(r2.w);
        float inv = 1.0f / (e0 + e1 + e3);
        q[8] = e0 * inv; q[9] = e1 * inv; q[10] = -1.0f; q[11] = e3 * inv;
    }
    {
        float e0 = __expf(r3.x), e1 = __expf(r3.y), e2 = __expf(r3.z);
        float inv = 1.0f / (e0 + e1 + e2);
        q[12] = e0 * inv; q[13] = e1 * inv; q[14] = e2 * inv; q[15] = -1.0f;
    }

    float m0 = det3(q[5],  q[6],  q[7],
                    q[9],  q[10], q[11],
                    q[13], q[14], q[15]);
    float m1 = det3(q[0],  q[2],  q[3],
                    q[8],  q[10], q[11],
                    q[12], q[14], q[15]);
    float m2 = det3(q[0],  q[1],  q[3],
                    q[4],  q[5],  q[7],
                    q[12], q[13], q[15]);
    float m3 = det3(q[0],  q[1],  q[2],
                    q[4],  q[5],  q[6],
                    q[8],  q[9],  q[10]);

    float invs = 1.0f / (m0 + m1 + m2 + m3);
    f32x4 v;
    v.x = m0 * invs;
    v.y = m1 * invs;
    v.z = m2 * invs;
    v.w = m3 * invs;
    return v;
}

// Exact-cover fast path: grid * 2048 float4 == n4, no bounds checks.
__global__ __launch_bounds__(256)
void stat_broadcast_exact(const float* __restrict__ logQ,
                          float* __restrict__ out) {
    f32x4 v = compute_pi(logQ);
    f32x4* __restrict__ out4 = reinterpret_cast<f32x4*>(out);
    int base = blockIdx.x * 2048 + (int)threadIdx.x;
    #pragma unroll
    for (int k = 0; k < 8; ++k) {
        __builtin_nontemporal_store(v, &out4[base + k * 256]);
    }
}

// Generic guarded path (only used if out_size isn't a multiple of 8192 floats).
__global__ __launch_bounds__(256)
void stat_broadcast_generic(const float* __restrict__ logQ,
                            float* __restrict__ out,
                            int n4, int n_total) {
    f32x4 v = compute_pi(logQ);
    f32x4* __restrict__ out4 = reinterpret_cast<f32x4*>(out);
    int base = blockIdx.x * 2048 + (int)threadIdx.x;
    #pragma unroll
    for (int k = 0; k < 8; ++k) {
        int i = base + k * 256;
        if (i < n4) __builtin_nontemporal_store(v, &out4[i]);
    }
    int tail = n4 << 2;
    if (tail < n_total) {
        int t = tail + blockIdx.x * blockDim.x + threadIdx.x;
        if (t < n_total) {
            int r = t & 3;
            out[t] = (r == 0) ? v.x : (r == 1) ? v.y : (r == 2) ? v.z : v.w;
        }
    }
}

extern "C" void kernel_launch(void* const* d_in, const int* in_sizes, int n_in,
                              void* d_out, int out_size, void* d_ws, size_t ws_size,
                              hipStream_t stream) {
    // inputs: 0: embeddings (unused), 1: site_positions (unused),
    //         2: log_Q_matrix (4x4 f32)
    const float* logQ = (const float*)d_in[2];
    float* out = (float*)d_out;

    int n4 = out_size >> 2;                 // 4,194,304 float4
    const int CHUNK = 2048;                 // 256 threads * 8 float4
    if ((out_size & 3) == 0 && (n4 % CHUNK) == 0) {
        int blocks = n4 / CHUNK;            // 2048 blocks exactly
        stat_broadcast_exact<<<blocks, 256, 0, stream>>>(logQ, out);
    } else {
        int blocks = (n4 + CHUNK - 1) / CHUNK;
        if (blocks < 1) blocks = 1;
        stat_broadcast_generic<<<blocks, 256, 0, stream>>>(logQ, out, n4, out_size);
    }
}